// Round 1
// baseline (387.247 us; speedup 1.0000x reference)
//
#include <hip/hip_runtime.h>
#include <hip/hip_bf16.h>
#include <math.h>

// Problem constants (from setup_inputs): B=4, S=2048, D=4096, 2B*S = 16384 rows.
#define PAD_ID 50256
#define S_LEN 2048
#define B_PAIRS 4

// ---------------------------------------------------------------------------
// Kernel 1: rewards[row] = dot(hidden_states[row,:], w)   (row = 0..16383)
// One wave (64 lanes) per row; 4 waves per 256-thread block.
// Memory-bound: streams 268 MB of hidden_states once; w (16 KB) is cache-hot.
// ---------------------------------------------------------------------------
__global__ __launch_bounds__(256) void rewards_kernel(
    const float4* __restrict__ hs,   // (nrows, D/4) as float4
    const float4* __restrict__ w4,   // (D/4,)
    float* __restrict__ rew,         // (nrows,)  == d_out + 1
    int D4, int nrows)
{
    const int wave = threadIdx.x >> 6;
    const int lane = threadIdx.x & 63;
    const int row  = blockIdx.x * 4 + wave;
    if (row >= nrows) return;

    const float4* rp = hs + (size_t)row * D4;
    float acc = 0.0f;
    // D4 = 1024 -> 16 iterations/lane, fully coalesced 16B/lane.
    #pragma unroll 4
    for (int j = lane; j < D4; j += 64) {
        float4 a = rp[j];
        float4 b = w4[j];
        acc = fmaf(a.x, b.x, acc);
        acc = fmaf(a.y, b.y, acc);
        acc = fmaf(a.z, b.z, acc);
        acc = fmaf(a.w, b.w, acc);
    }
    // wave-64 butterfly reduce
    #pragma unroll
    for (int off = 32; off > 0; off >>= 1)
        acc += __shfl_down(acc, off, 64);
    if (lane == 0) rew[row] = acc;
}

// ---------------------------------------------------------------------------
// Kernel 2: per-pair indices, masked means, end scores, pairwise loss.
// Single 256-thread block; total work ~4 * 2048 elements — launch-overhead
// scale. Runs after kernel 1 on the same stream (reads rewards from d_out+1).
// Output layout: out[0]=loss, out[1..16384]=rewards (written by kernel 1),
// out[16385+ b]=chosen_mean, +4 rejected_mean, +8 chosen_end, +12 rejected_end.
// ---------------------------------------------------------------------------
__device__ inline float wave_sum(float v) {
    #pragma unroll
    for (int off = 32; off > 0; off >>= 1) v += __shfl_down(v, off, 64);
    return v;
}
__device__ inline int wave_min(int v) {
    #pragma unroll
    for (int off = 32; off > 0; off >>= 1) v = min(v, __shfl_down(v, off, 64));
    return v;
}

__global__ __launch_bounds__(256) void scores_kernel(
    const float* __restrict__ rew,   // (2B, S) == d_out + 1
    const int*   __restrict__ ids,   // (2B, S)
    float* __restrict__ out)
{
    __shared__ int   si[3][4];
    __shared__ float sf[3][4];
    __shared__ int   s_div, s_end;
    __shared__ float s_loss;

    const int tid  = threadIdx.x;
    const int lane = tid & 63;
    const int wave = tid >> 6;

    if (tid == 0) s_loss = 0.0f;
    __syncthreads();

    for (int b = 0; b < B_PAIRS; ++b) {
        const int*   ch = ids + (size_t)b * S_LEN;
        const int*   rj = ids + (size_t)(B_PAIRS + b) * S_LEN;
        const float* cr = rew + (size_t)b * S_LEN;
        const float* rr = rew + (size_t)(B_PAIRS + b) * S_LEN;

        // --- first-index scans ---
        int ldiv = S_LEN, lc = S_LEN, lr = S_LEN;
        for (int s = tid; s < S_LEN; s += 256) {
            int c = ch[s], r = rj[s];
            if (c != r)      ldiv = min(ldiv, s);
            if (c == PAD_ID) lc   = min(lc, s);
            if (r == PAD_ID) lr   = min(lr, s);
        }
        ldiv = wave_min(ldiv); lc = wave_min(lc); lr = wave_min(lr);
        if (lane == 0) { si[0][wave] = ldiv; si[1][wave] = lc; si[2][wave] = lr; }
        __syncthreads();
        if (tid == 0) {
            int dv = min(min(si[0][0], si[0][1]), min(si[0][2], si[0][3]));
            int ci = min(min(si[1][0], si[1][1]), min(si[1][2], si[1][3]));
            int ri = min(min(si[2][0], si[2][1]), min(si[2][2], si[2][3]));
            s_div = dv;
            s_end = max(ci, ri);
        }
        __syncthreads();
        const int dv = s_div, en = s_end;

        // --- masked sums over [dv, en) ---
        float sc = 0.0f, sr = 0.0f, sl = 0.0f;
        for (int s = dv + tid; s < en; s += 256) {
            float cv = cr[s], rv = rr[s];
            sc += cv;
            sr += rv;
            float x = cv - rv;
            // -log_sigmoid(x) = softplus(-x), numerically stable form:
            sl += fmaxf(-x, 0.0f) + log1pf(expf(-fabsf(x)));
        }
        sc = wave_sum(sc); sr = wave_sum(sr); sl = wave_sum(sl);
        if (lane == 0) { sf[0][wave] = sc; sf[1][wave] = sr; sf[2][wave] = sl; }
        __syncthreads();
        if (tid == 0) {
            float tsc = sf[0][0] + sf[0][1] + sf[0][2] + sf[0][3];
            float tsr = sf[1][0] + sf[1][1] + sf[1][2] + sf[1][3];
            float tsl = sf[2][0] + sf[2][1] + sf[2][2] + sf[2][3];
            int cnt_i = en - dv;
            if (cnt_i < 1) cnt_i = 1;
            float inv_cnt = 1.0f / (float)cnt_i;
            int last = en - 1;
            if (last < 0) last = 0;
            const int base = 1 + 2 * B_PAIRS * S_LEN;   // 1 + 16384
            out[base + 0 * B_PAIRS + b] = tsc * inv_cnt;  // chosen_mean_scores
            out[base + 1 * B_PAIRS + b] = tsr * inv_cnt;  // rejected_mean_scores
            out[base + 2 * B_PAIRS + b] = cr[last];       // chosen_end_scores
            out[base + 3 * B_PAIRS + b] = rr[last];       // rejected_end_scores
            s_loss += tsl * inv_cnt;
        }
        __syncthreads();
    }
    if (tid == 0) out[0] = s_loss / (float)B_PAIRS;
}

extern "C" void kernel_launch(void* const* d_in, const int* in_sizes, int n_in,
                              void* d_out, int out_size, void* d_ws, size_t ws_size,
                              hipStream_t stream) {
    const float* hs  = (const float*)d_in[0];   // (2B, S, D) fp32
    const float* w   = (const float*)d_in[1];   // (D,) fp32
    const int*   ids = (const int*)d_in[2];     // (2B, S) int

    float* out = (float*)d_out;
    float* rew = out + 1;                       // rewards live at out[1..16384]

    const int D     = in_sizes[1];              // 4096
    const int D4    = D / 4;                    // 1024
    const int nrows = in_sizes[0] / D;          // 16384

    // Kernel 1: GEMV rewards (memory-bound, ~268 MB stream)
    const int blocks = (nrows + 3) / 4;
    rewards_kernel<<<blocks, 256, 0, stream>>>(
        (const float4*)hs, (const float4*)w, rew, D4, nrows);

    // Kernel 2: indices + means + end scores + loss (single block, tiny)
    scores_kernel<<<1, 256, 0, stream>>>(rew, ids, out);
}

// Round 2
// 382.065 us; speedup vs baseline: 1.0136x; 1.0136x over previous
//
#include <hip/hip_runtime.h>
#include <hip/hip_bf16.h>
#include <math.h>

// Problem constants (from setup_inputs): B=4, S=2048, D=4096, 2B*S = 16384 rows.
#define PAD_ID 50256
#define S_LEN 2048
#define B_PAIRS 4
#define D4_C 1024          // D/4 = 4096/4
#define ROWS_PER_WAVE 2    // each wave computes 2 rows, reusing w-in-registers

// ---------------------------------------------------------------------------
// Kernel 1: rewards[row] = dot(hidden_states[row,:], w)
// 256-thread blocks (4 waves); each wave handles ROWS_PER_WAVE consecutive
// rows. w is hoisted into 16 float4 registers per lane (loaded once per wave,
// reused across rows) so the inner loop is a PURE hs stream: 16 coalesced
// float4 loads per row, fully unrolled, 2 accumulators to break the FMA chain.
// Memory-bound: streams 268 MB of hidden_states once.
// ---------------------------------------------------------------------------
__global__ __launch_bounds__(256) void rewards_kernel(
    const float4* __restrict__ hs,   // (nrows, D/4) as float4
    const float4* __restrict__ w4,   // (D/4,)
    float* __restrict__ rew,         // (nrows,)  == d_out + 1
    int nrows)
{
    const int wave = threadIdx.x >> 6;
    const int lane = threadIdx.x & 63;
    const int row0 = (blockIdx.x * 4 + wave) * ROWS_PER_WAVE;

    // Hoist w into registers: lane holds w4[lane + 64k], k = 0..15 (64 VGPRs).
    float4 wv[16];
    #pragma unroll
    for (int k = 0; k < 16; ++k)
        wv[k] = w4[lane + 64 * k];

    #pragma unroll
    for (int r = 0; r < ROWS_PER_WAVE; ++r) {
        const int row = row0 + r;
        if (row >= nrows) return;
        const float4* rp = hs + (size_t)row * D4_C;

        float acc0 = 0.0f, acc1 = 0.0f;
        #pragma unroll
        for (int k = 0; k < 16; k += 2) {
            float4 a0 = rp[lane + 64 * k];
            float4 a1 = rp[lane + 64 * (k + 1)];
            acc0 = fmaf(a0.x, wv[k].x, acc0);
            acc0 = fmaf(a0.y, wv[k].y, acc0);
            acc0 = fmaf(a0.z, wv[k].z, acc0);
            acc0 = fmaf(a0.w, wv[k].w, acc0);
            acc1 = fmaf(a1.x, wv[k + 1].x, acc1);
            acc1 = fmaf(a1.y, wv[k + 1].y, acc1);
            acc1 = fmaf(a1.z, wv[k + 1].z, acc1);
            acc1 = fmaf(a1.w, wv[k + 1].w, acc1);
        }
        float acc = acc0 + acc1;

        // wave-64 butterfly reduce
        #pragma unroll
        for (int off = 32; off > 0; off >>= 1)
            acc += __shfl_down(acc, off, 64);
        if (lane == 0) rew[row] = acc;
    }
}

// ---------------------------------------------------------------------------
// Kernel 2: per-pair indices, masked means, end scores, pairwise loss.
// Single 256-thread block; total work ~4 * 2048 elements.
// Output layout: out[0]=loss, out[1..16384]=rewards (written by kernel 1),
// out[16385+ b]=chosen_mean, +4 rejected_mean, +8 chosen_end, +12 rejected_end.
// ---------------------------------------------------------------------------
__device__ inline float wave_sum(float v) {
    #pragma unroll
    for (int off = 32; off > 0; off >>= 1) v += __shfl_down(v, off, 64);
    return v;
}
__device__ inline int wave_min(int v) {
    #pragma unroll
    for (int off = 32; off > 0; off >>= 1) v = min(v, __shfl_down(v, off, 64));
    return v;
}

__global__ __launch_bounds__(256) void scores_kernel(
    const float* __restrict__ rew,   // (2B, S) == d_out + 1
    const int*   __restrict__ ids,   // (2B, S)
    float* __restrict__ out)
{
    __shared__ int   si[3][4];
    __shared__ float sf[3][4];
    __shared__ int   s_div, s_end;
    __shared__ float s_loss;

    const int tid  = threadIdx.x;
    const int lane = tid & 63;
    const int wave = tid >> 6;

    if (tid == 0) s_loss = 0.0f;
    __syncthreads();

    for (int b = 0; b < B_PAIRS; ++b) {
        const int*   ch = ids + (size_t)b * S_LEN;
        const int*   rj = ids + (size_t)(B_PAIRS + b) * S_LEN;
        const float* cr = rew + (size_t)b * S_LEN;
        const float* rr = rew + (size_t)(B_PAIRS + b) * S_LEN;

        // --- first-index scans ---
        int ldiv = S_LEN, lc = S_LEN, lr = S_LEN;
        for (int s = tid; s < S_LEN; s += 256) {
            int c = ch[s], r = rj[s];
            if (c != r)      ldiv = min(ldiv, s);
            if (c == PAD_ID) lc   = min(lc, s);
            if (r == PAD_ID) lr   = min(lr, s);
        }
        ldiv = wave_min(ldiv); lc = wave_min(lc); lr = wave_min(lr);
        if (lane == 0) { si[0][wave] = ldiv; si[1][wave] = lc; si[2][wave] = lr; }
        __syncthreads();
        if (tid == 0) {
            int dv = min(min(si[0][0], si[0][1]), min(si[0][2], si[0][3]));
            int ci = min(min(si[1][0], si[1][1]), min(si[1][2], si[1][3]));
            int ri = min(min(si[2][0], si[2][1]), min(si[2][2], si[2][3]));
            s_div = dv;
            s_end = max(ci, ri);
        }
        __syncthreads();
        const int dv = s_div, en = s_end;

        // --- masked sums over [dv, en) ---
        float sc = 0.0f, sr = 0.0f, sl = 0.0f;
        for (int s = dv + tid; s < en; s += 256) {
            float cv = cr[s], rv = rr[s];
            sc += cv;
            sr += rv;
            float x = cv - rv;
            // -log_sigmoid(x) = softplus(-x), numerically stable form:
            sl += fmaxf(-x, 0.0f) + log1pf(expf(-fabsf(x)));
        }
        sc = wave_sum(sc); sr = wave_sum(sr); sl = wave_sum(sl);
        if (lane == 0) { sf[0][wave] = sc; sf[1][wave] = sr; sf[2][wave] = sl; }
        __syncthreads();
        if (tid == 0) {
            float tsc = sf[0][0] + sf[0][1] + sf[0][2] + sf[0][3];
            float tsr = sf[1][0] + sf[1][1] + sf[1][2] + sf[1][3];
            float tsl = sf[2][0] + sf[2][1] + sf[2][2] + sf[2][3];
            int cnt_i = en - dv;
            if (cnt_i < 1) cnt_i = 1;
            float inv_cnt = 1.0f / (float)cnt_i;
            int last = en - 1;
            if (last < 0) last = 0;
            const int base = 1 + 2 * B_PAIRS * S_LEN;   // 1 + 16384
            out[base + 0 * B_PAIRS + b] = tsc * inv_cnt;  // chosen_mean_scores
            out[base + 1 * B_PAIRS + b] = tsr * inv_cnt;  // rejected_mean_scores
            out[base + 2 * B_PAIRS + b] = cr[last];       // chosen_end_scores
            out[base + 3 * B_PAIRS + b] = rr[last];       // rejected_end_scores
            s_loss += tsl * inv_cnt;
        }
        __syncthreads();
    }
    if (tid == 0) out[0] = s_loss / (float)B_PAIRS;
}

extern "C" void kernel_launch(void* const* d_in, const int* in_sizes, int n_in,
                              void* d_out, int out_size, void* d_ws, size_t ws_size,
                              hipStream_t stream) {
    const float* hs  = (const float*)d_in[0];   // (2B, S, D) fp32
    const float* w   = (const float*)d_in[1];   // (D,) fp32
    const int*   ids = (const int*)d_in[2];     // (2B, S) int

    float* out = (float*)d_out;
    float* rew = out + 1;                       // rewards live at out[1..16384]

    const int nrows = in_sizes[0] / in_sizes[1];   // 16384

    // Kernel 1: GEMV rewards (memory-bound, ~268 MB stream)
    const int rows_per_block = 4 * ROWS_PER_WAVE;  // 8
    const int blocks = (nrows + rows_per_block - 1) / rows_per_block;
    rewards_kernel<<<blocks, 256, 0, stream>>>(
        (const float4*)hs, (const float4*)w, rew, nrows);

    // Kernel 2: indices + means + end scores + loss (single block, tiny)
    scores_kernel<<<1, 256, 0, stream>>>(rew, ids, out);
}